// Round 10
// baseline (201.369 us; speedup 1.0000x reference)
//
#include <hip/hip_runtime.h>
#include <hip/hip_bf16.h>

using bf16 = __hip_bfloat16;
typedef __bf16 bf16x8_t __attribute__((ext_vector_type(8)));
typedef float f32x4_t __attribute__((ext_vector_type(4)));

// ---------------------------------------------------------------- helpers
__device__ __forceinline__ void gl16(bf16* l, const bf16* g) {
  // async global->LDS, 16B per lane; LDS dest must be linear (base + lane*16)
  __builtin_amdgcn_global_load_lds(
      (const __attribute__((address_space(1))) unsigned int*)g,
      (__attribute__((address_space(3))) unsigned int*)l, 16, 0, 0);
}

#define BARRIER() do { asm volatile("" ::: "memory"); __builtin_amdgcn_s_barrier(); asm volatile("" ::: "memory"); } while (0)
#define WAITVM(N) asm volatile("s_waitcnt vmcnt(" #N ")" ::: "memory")
#define SCHED0() __builtin_amdgcn_sched_barrier(0)

// ---------------------------------------------------------------- fused prep: cvt x + transpose both W
__global__ __launch_bounds__(256) void prep_fused(const float* __restrict__ x,
                                                  const float* __restrict__ Wqkv,
                                                  const float* __restrict__ Wout,
                                                  bf16* __restrict__ xb,
                                                  bf16* __restrict__ w1t,
                                                  bf16* __restrict__ w2t) {
  __shared__ float t[32][33];
  const int bid = blockIdx.x;
  if (bid < 16384) {  // cvt: 4 f32 per thread
    int i = bid * 256 + threadIdx.x;
    float4 v = ((const float4*)x)[i];
    union { ushort4 u; bf16 b[4]; } o;
    o.b[0] = __float2bfloat16(v.x);
    o.b[1] = __float2bfloat16(v.y);
    o.b[2] = __float2bfloat16(v.z);
    o.b[3] = __float2bfloat16(v.w);
    ((ushort4*)xb)[i] = o.u;
    return;
  }
  const float* in; bf16* out; int R, C, gx, gy;
  if (bid < 16384 + 3072) {
    int idx = bid - 16384; in = Wqkv; out = w1t; R = 1024; C = 3072;
    gx = idx % 96; gy = idx / 96;
  } else {
    int idx = bid - 16384 - 3072; in = Wout; out = w2t; R = 1024; C = 1024;
    gx = idx & 31; gy = idx >> 5;
  }
  int bx = gx * 32, by = gy * 32;
  int tx = threadIdx.x & 31, ty = threadIdx.x >> 5;  // ty 0..7
#pragma unroll
  for (int r = 0; r < 32; r += 8)
    t[ty + r][tx] = in[(size_t)(by + ty + r) * C + bx + tx];
  __syncthreads();
#pragma unroll
  for (int r = 0; r < 32; r += 8)
    out[(size_t)(bx + ty + r) * R + by + tx] = __float2bfloat16(t[tx][ty + r]);
}

// ---------------------------------------------------------------- 256x256 bf16 GEMM, R5 schedule + zero-VALU steady state
// C[M=16384, N=NWGX*256] = A @ Bt^T + bias. K=1024 (16 K-steps of BK=64), 1 tile/block.
// LDS elem layout: A: [h][parity][8192] at 0..32767; B same at 32768..65535 (128 KiB).
//   -> every ds_read = persistent per-lane pointer + compile-time offset (max 55296 B).
// Staging: 8 persistent global pointers + static gs*64-elem offsets (folds to offset:imm).
// Schedule = R5 (verified): 4 phases/step, 1 barrier each; fragments read one phase ahead;
// ph4 stages B(g+2,h0) then WAITVM(4) -> step g+1 fully resident, {A,B}(g+2,h0) in flight.
// x2-unrolled body (parity static), steps 14/15 peeled (vm(0) at 14).

template <int H, int P>
__device__ __forceinline__ void readAx(const bf16* pA0, const bf16* pA1, bf16x8_t (&af)[4][2]) {
#pragma unroll
  for (int mi = 0; mi < 4; ++mi) {
    af[mi][0] = *(const bf16x8_t*)(pA0 + mi * 1024 + H * 16384 + P * 8192);
    af[mi][1] = *(const bf16x8_t*)(pA1 + mi * 1024 + H * 16384 + P * 8192);
  }
}
template <int H, int P>
__device__ __forceinline__ void readBx(const bf16* pB0, const bf16* pB1, bf16x8_t (&bfr)[2][2]) {
#pragma unroll
  for (int ni = 0; ni < 2; ++ni) {
    bfr[ni][0] = *(const bf16x8_t*)(pB0 + ni * 1024 + H * 16384 + P * 8192);
    bfr[ni][1] = *(const bf16x8_t*)(pB1 + ni * 1024 + H * 16384 + P * 8192);
  }
}

template <int MH, int NH>
__device__ __forceinline__ void mfma16(bf16x8_t (&af)[4][2], bf16x8_t (&bfr)[2][2],
                                       f32x4_t (&acc)[8][4]) {
  __builtin_amdgcn_s_setprio(1);
#pragma unroll
  for (int mi = 0; mi < 4; ++mi)
#pragma unroll
    for (int ni = 0; ni < 2; ++ni) {
      f32x4_t& a = acc[MH * 4 + mi][NH * 2 + ni];
      a = __builtin_amdgcn_mfma_f32_16x16x32_bf16(af[mi][0], bfr[ni][0], a, 0, 0, 0);
      a = __builtin_amdgcn_mfma_f32_16x16x32_bf16(af[mi][1], bfr[ni][1], a, 0, 0, 0);
    }
  __builtin_amdgcn_s_setprio(0);
}

template <int OUT_BF16, int NG, int NWGX>
__global__ __launch_bounds__(512, 2) void gemm256s(const bf16* __restrict__ A,
                                                   const bf16* __restrict__ Bt,
                                                   const float* __restrict__ bias,
                                                   void* __restrict__ Cv) {
  constexpr int K = 1024;
  constexpr int N = NWGX * 256;
  constexpr int Q = NG / 8;  // bijective XCD swizzle (NG % 8 == 0)
  __shared__ __align__(16) bf16 lds[65536];
  const int tid = threadIdx.x, bx = blockIdx.x;
  const int swz = (bx & 7) * Q + (bx >> 3);
  const int m0 = (swz / NWGX) * 256, n0 = (swz % NWGX) * 256;

  const int wid = tid >> 6, lane = tid & 63;
  const int wr = wid >> 2, wc = wid & 3;
  const int lr = lane & 15, lg = lane >> 4;
  const int exr = (lr & 7) << 3;
  const int srow = tid >> 3;
  const int colg = ((((tid & 7) * 16) ^ ((srow & 7) << 4)) >> 1);
  const int browc0 = (srow >> 5) * 64 + (srow & 31);

  // persistent global staging pointers (per half: lo = rows r<128, hi = +128)
  const bf16* gA0l = A + (size_t)(m0 + srow) * K + colg;
  const bf16* gA0h = gA0l + (size_t)128 * K;
  const bf16* gA1l = A + (size_t)(m0 + 64 + srow) * K + colg;
  const bf16* gA1h = gA1l + (size_t)128 * K;
  const bf16* gB0l = Bt + (size_t)(n0 + browc0) * K + colg;
  const bf16* gB0h = gB0l + (size_t)128 * K;
  const bf16* gB1l = Bt + (size_t)(n0 + browc0 + 32) * K + colg;
  const bf16* gB1h = gB1l + (size_t)128 * K;
  bf16* ldsSt = lds + tid * 8;

  // persistent per-lane LDS read pointers (chunk 0 / chunk 1 of each b128 pair)
  const bf16* pA0 = lds + (wr * 64 + lr) * 64 + ((lg * 8) ^ exr);
  const bf16* pA1 = lds + (wr * 64 + lr) * 64 + ((32 + lg * 8) ^ exr);
  const bf16* pB0 = lds + 32768 + (wc * 32 + lr) * 64 + ((lg * 8) ^ exr);
  const bf16* pB1 = lds + 32768 + (wc * 32 + lr) * 64 + ((32 + lg * 8) ^ exr);

  auto stA = [&](const bf16* lo, const bf16* hi, int loff) {
    gl16(ldsSt + loff, lo); gl16(ldsSt + loff + 4096, hi);
  };
  auto stB = [&](const bf16* lo, const bf16* hi, int loff) {
    gl16(ldsSt + 32768 + loff, lo); gl16(ldsSt + 32768 + loff + 4096, hi);
  };

  f32x4_t acc[8][4] = {};
  bf16x8_t af1[4][2], af2[4][2], b0[2][2], b1[2][2];

  // prologue: step0 all halves (p0) + step1 h0 (p1); vm(4) leaves {A,B}(1,h0) in flight
  stA(gA0l, gA0h, 0);                 stB(gB0l, gB0h, 0);
  stA(gA1l, gA1h, 16384);             stB(gB1l, gB1h, 16384);
  stA(gA0l + 64, gA0h + 64, 8192);    stB(gB0l + 64, gB0h + 64, 8192);
  WAITVM(4);
  BARRIER();
  readAx<0, 0>(pA0, pA1, af1);
  readBx<0, 0>(pB0, pB1, b0);

  for (int gs = 0; gs < 14; gs += 2) {
    {  // ---- even step g = gs (cb parity 0)
      stA(gA1l + (gs + 1) * 64, gA1h + (gs + 1) * 64, 16384 + 8192);
      BARRIER();
      readBx<1, 0>(pB0, pB1, b1); SCHED0();
      mfma16<0, 0>(af1, b0, acc);

      stB(gB1l + (gs + 1) * 64, gB1h + (gs + 1) * 64, 16384 + 8192);
      BARRIER();
      readAx<1, 0>(pA0, pA1, af2); SCHED0();
      mfma16<0, 1>(af1, b1, acc);

      stA(gA0l + (gs + 2) * 64, gA0h + (gs + 2) * 64, 0);
      BARRIER();
      mfma16<1, 0>(af2, b0, acc);

      stB(gB0l + (gs + 2) * 64, gB0h + (gs + 2) * 64, 0);
      WAITVM(4);
      BARRIER();
      readAx<0, 1>(pA0, pA1, af1);
      readBx<0, 1>(pB0, pB1, b0); SCHED0();
      mfma16<1, 1>(af2, b1, acc);
    }
    {  // ---- odd step g = gs+1 (cb parity 1)
      stA(gA1l + (gs + 2) * 64, gA1h + (gs + 2) * 64, 16384);
      BARRIER();
      readBx<1, 1>(pB0, pB1, b1); SCHED0();
      mfma16<0, 0>(af1, b0, acc);

      stB(gB1l + (gs + 2) * 64, gB1h + (gs + 2) * 64, 16384);
      BARRIER();
      readAx<1, 1>(pA0, pA1, af2); SCHED0();
      mfma16<0, 1>(af1, b1, acc);

      stA(gA0l + (gs + 3) * 64, gA0h + (gs + 3) * 64, 8192);
      BARRIER();
      mfma16<1, 0>(af2, b0, acc);

      stB(gB0l + (gs + 3) * 64, gB0h + (gs + 3) * 64, 8192);
      WAITVM(4);
      BARRIER();
      readAx<0, 0>(pA0, pA1, af1);
      readBx<0, 0>(pB0, pB1, b0); SCHED0();
      mfma16<1, 1>(af2, b1, acc);
    }
  }
  {  // ---- peeled step 14 (even, cb p0): stage only step-15 h1; drain all at ph4
    stA(gA1l + 15 * 64, gA1h + 15 * 64, 16384 + 8192);
    BARRIER();
    readBx<1, 0>(pB0, pB1, b1); SCHED0();
    mfma16<0, 0>(af1, b0, acc);

    stB(gB1l + 15 * 64, gB1h + 15 * 64, 16384 + 8192);
    BARRIER();
    readAx<1, 0>(pA0, pA1, af2); SCHED0();
    mfma16<0, 1>(af1, b1, acc);

    BARRIER();
    mfma16<1, 0>(af2, b0, acc);

    WAITVM(0);
    BARRIER();
    readAx<0, 1>(pA0, pA1, af1);
    readBx<0, 1>(pB0, pB1, b0); SCHED0();
    mfma16<1, 1>(af2, b1, acc);
  }
  {  // ---- peeled step 15 (odd, cb p1): compute only
    BARRIER();
    readBx<1, 1>(pB0, pB1, b1); SCHED0();
    mfma16<0, 0>(af1, b0, acc);
    BARRIER();
    readAx<1, 1>(pA0, pA1, af2); SCHED0();
    mfma16<0, 1>(af1, b1, acc);
    BARRIER();
    mfma16<1, 0>(af2, b0, acc);
    BARRIER();
    mfma16<1, 1>(af2, b1, acc);
  }

  // epilogue dump: n innermost so each 64B C-line completes back-to-back
  float bv[4];
#pragma unroll
  for (int n = 0; n < 4; ++n) bv[n] = bias[n0 + wc * 64 + n * 16 + lr];
#pragma unroll
  for (int m = 0; m < 8; ++m) {
    int row = m0 + wr * 128 + m * 16 + lg * 4;
#pragma unroll
    for (int j = 0; j < 4; ++j) {
#pragma unroll
      for (int n = 0; n < 4; ++n) {
        int col = n0 + wc * 64 + n * 16 + lr;
        float v = acc[m][n][j] + bv[n];
        if (OUT_BF16)
          ((bf16*)Cv)[(size_t)(row + j) * N + col] = __float2bfloat16(v);
        else
          ((float*)Cv)[(size_t)(row + j) * N + col] = v;
      }
    }
  }
}

// ---------------------------------------------------------------- per-token head-mixing attention (MFMA)
// qkv[t][0:1024]=q, [1024:2048]=k, [2048:3072]=v ; head layout idx = h*64+d
// logits[qh][kh] = 0.125 * dot(q[qh], k[kh]); softmax over kh; out[qh][d] = sum_kh p*v[kh][d]
#define PSTR 48
__global__ __launch_bounds__(256) void attn_tok(const bf16* __restrict__ qkv,
                                                bf16* __restrict__ out) {
  __shared__ __align__(16) bf16 vs[4][1024];
  __shared__ __align__(16) bf16 ps[4][16 * PSTR];
  const int w = threadIdx.x >> 6, l = threadIdx.x & 63;
  const int t = blockIdx.x * 4 + w;
  const int lr = l & 15, lg = l >> 4;
  const bf16* base = qkv + (size_t)t * 3072;

  bf16x8_t v0 = *(const bf16x8_t*)(base + 2048 + l * 16);
  bf16x8_t v1 = *(const bf16x8_t*)(base + 2048 + l * 16 + 8);
  *(bf16x8_t*)(&vs[w][l * 16]) = v0;
  *(bf16x8_t*)(&vs[w][l * 16 + 8]) = v1;

  *(unsigned long long*)(&ps[w][(l >> 2) * PSTR + 16 + (l & 3) * 4]) = 0ULL;

  const bf16* qp = base + lr * 64 + lg * 8;
  const bf16* kp = base + 1024 + lr * 64 + lg * 8;
  bf16x8_t qa0 = *(const bf16x8_t*)qp;
  bf16x8_t ka0 = *(const bf16x8_t*)kp;
  bf16x8_t qa1 = *(const bf16x8_t*)(qp + 32);
  bf16x8_t ka1 = *(const bf16x8_t*)(kp + 32);
  f32x4_t s = {};
  s = __builtin_amdgcn_mfma_f32_16x16x32_bf16(qa0, ka0, s, 0, 0, 0);
  s = __builtin_amdgcn_mfma_f32_16x16x32_bf16(qa1, ka1, s, 0, 0, 0);

#pragma unroll
  for (int j = 0; j < 4; ++j) {
    float x = s[j] * 0.125f;
    float mx = x;
#pragma unroll
    for (int off = 8; off; off >>= 1) mx = fmaxf(mx, __shfl_xor(mx, off, 16));
    float e = __expf(x - mx);
    float sum = e;
#pragma unroll
    for (int off = 8; off; off >>= 1) sum += __shfl_xor(sum, off, 16);
    ps[w][(lg * 4 + j) * PSTR + lr] = __float2bfloat16(e / sum);
  }

  bf16x8_t pf = *(const bf16x8_t*)(&ps[w][lr * PSTR + lg * 8]);
  bf16x8_t vf[4] = {};
  if (l < 32) {
#pragma unroll
    for (int c = 0; c < 4; ++c)
#pragma unroll
      for (int j = 0; j < 8; ++j)
        vf[c][j] = (__bf16)vs[w][(lg * 8 + j) * 64 + c * 16 + lr];
  }
  f32x4_t o[4] = {};
#pragma unroll
  for (int c = 0; c < 4; ++c)
    o[c] = __builtin_amdgcn_mfma_f32_16x16x32_bf16(pf, vf[c], o[c], 0, 0, 0);

  bf16* ob = out + (size_t)t * 1024;
#pragma unroll
  for (int c = 0; c < 4; ++c)
#pragma unroll
    for (int j = 0; j < 4; ++j)
      ob[(lg * 4 + j) * 64 + c * 16 + lr] = __float2bfloat16(o[c][j]);
}

// ---------------------------------------------------------------- launch
extern "C" void kernel_launch(void* const* d_in, const int* in_sizes, int n_in,
                              void* d_out, int out_size, void* d_ws, size_t ws_size,
                              hipStream_t stream) {
  const float* x    = (const float*)d_in[0];  // [16384,1024]
  const float* Wqkv = (const float*)d_in[1];  // [1024,3072]
  const float* bqkv = (const float*)d_in[2];  // [3072]
  const float* Wout = (const float*)d_in[3];  // [1024,1024]
  const float* bout = (const float*)d_in[4];  // [1024]
  float* y = (float*)d_out;                   // [16384,1024]

  const int T = 16384, HD = 1024, N1 = 3072;

  char* ws = (char*)d_ws;
  size_t off = 0;
  bf16* xb  = (bf16*)(ws + off); off += (size_t)T * HD * 2;
  bf16* w1t = (bf16*)(ws + off); off += (size_t)N1 * HD * 2;
  bf16* w2t = (bf16*)(ws + off); off += (size_t)HD * HD * 2;
  bf16* qkv = (bf16*)(ws + off); off += (size_t)T * N1 * 2;
  if (ws_size < off) return;
  bf16* ao = xb;  // xb dead after GEMM1; reuse as attention output

  prep_fused<<<16384 + 3072 + 1024, 256, 0, stream>>>(x, Wqkv, Wout, xb, w1t, w2t);
  gemm256s<1, 768, 12><<<768, 512, 0, stream>>>(xb, w1t, bqkv, qkv);
  attn_tok<<<T / 4, 256, 0, stream>>>(qkv, ao);
  gemm256s<0, 256, 4><<<256, 512, 0, stream>>>(ao, w2t, bout, y);
}